// Round 1
// baseline (67.469 us; speedup 1.0000x reference)
//
#include <hip/hip_runtime.h>
#include <hip/hip_bf16.h>
#include <math.h>

// Problem constants (DeepFM)
#define BTOT   16384
#define NF     26
#define VOCAB  100000
#define EDIM   16
#define DD     13
#define KPAD   448      // 429 padded to 14*32
#define KREAL  429
#define N1     256
#define N2     128

typedef __attribute__((ext_vector_type(8))) short bf16x8;
typedef __attribute__((ext_vector_type(4))) float f32x4;

static __device__ __forceinline__ bf16x8 ldb8(const __hip_bfloat16* p) {
  return *reinterpret_cast<const bf16x8*>(p);
}

// ---------------------------------------------------------------------------
// Kernel 1: repack W1 [256][429] f32 -> W1f bf16 in B-fragment layout
//   element (k, n) stored at W1f[((k>>3)*N1 + n)*8 + (k&7)], zero pad k>=429.
// Same for W2 [128][256] -> W2f.
// ---------------------------------------------------------------------------
__global__ void convert_weights(const float* __restrict__ W1,
                                const float* __restrict__ W2,
                                __hip_bfloat16* __restrict__ W1f,
                                __hip_bfloat16* __restrict__ W2f) {
  int bid = blockIdx.x;
  int tid = threadIdx.x;
  if (bid < 448) {               // W1: k = bid (0..447), n = tid (0..255)
    int k = bid, n = tid;
    float v = (k < KREAL) ? W1[(size_t)n * KREAL + k] : 0.f;
    W1f[(((size_t)(k >> 3)) * N1 + n) * 8 + (k & 7)] = __float2bfloat16(v);
  } else {                       // W2: 256x128 elements, 128 blocks
    int g = (bid - 448) * 256 + tid;
    int k = g >> 7;              // 0..255
    int n = g & 127;             // 0..127
    float v = W2[(size_t)n * 256 + k];
    W2f[(((size_t)(k >> 3)) * N2 + n) * 8 + (k & 7)] = __float2bfloat16(v);
  }
}

// ---------------------------------------------------------------------------
// Kernel 2: embedding gather + FM first/second order (fp32), build H (bf16).
// Block = 256 threads = 16 samples x 16 lanes (lane = embedding dim e).
// ---------------------------------------------------------------------------
__global__ __launch_bounds__(256) void embed_fm(
    const int* __restrict__ Xs, const float* __restrict__ Xd,
    const float* __restrict__ linW, const float* __restrict__ fmW,
    const float* __restrict__ denseW, const float* __restrict__ denseB,
    __hip_bfloat16* __restrict__ H, float* __restrict__ fmlogit) {
  const int e  = threadIdx.x & 15;
  const int sl = threadIdx.x >> 4;
  const size_t b = (size_t)blockIdx.x * 16 + sl;

  float sum = 0.f, sumsq = 0.f;
  __hip_bfloat16* Hrow = H + b * KPAD;

#pragma unroll
  for (int f = 0; f < NF; ++f) {
    int idx = Xs[b * NF + f];
    float v = fmW[((size_t)f * VOCAB + idx) * EDIM + e];
    sum += v;
    sumsq += v * v;
    Hrow[f * EDIM + e] = __float2bfloat16(v);
  }
  float cross = sum * sum - sumsq;
#pragma unroll
  for (int off = 1; off < 16; off <<= 1)
    cross += __shfl_xor(cross, off, 16);

  // dense features into H tail + zero padding (429..447)
  float xd = (e < DD) ? Xd[b * DD + e] : 0.f;
  Hrow[416 + e] = __float2bfloat16(xd);
  Hrow[432 + e] = __float2bfloat16(0.f);

  if (e == 0) {
    float lin = denseB[0];
#pragma unroll
    for (int f = 0; f < NF; ++f)
      lin += linW[(size_t)f * VOCAB + Xs[b * NF + f]];
#pragma unroll
    for (int d = 0; d < DD; ++d)
      lin += Xd[b * DD + d] * denseW[d];
    fmlogit[b] = lin + 0.5f * cross;
  }
}

// ---------------------------------------------------------------------------
// Kernel 3: GEMM1  C[B,256] = H[B,448] x W1^T, +b1, ReLU -> H2 bf16 [B][256]
// Block 256 thr = 4 waves; block tile 64 rows x 64 cols; wave = 16 cols.
// mfma_f32_16x16x32_bf16: A lane&15=row, 8 contig k by lane>>4; B lane&15=col;
// C/D: col=lane&15, row=(lane>>4)*4+reg.
// ---------------------------------------------------------------------------
__global__ __launch_bounds__(256) void gemm1(
    const __hip_bfloat16* __restrict__ Hm, const __hip_bfloat16* __restrict__ W1f,
    const float* __restrict__ b1, __hip_bfloat16* __restrict__ H2) {
  const int wave = threadIdx.x >> 6;
  const int lane = threadIdx.x & 63;
  const int m0 = blockIdx.x * 64;
  const int n0 = blockIdx.y * 64 + wave * 16;
  const int lr = lane & 15;       // A row / B col
  const int kg = lane >> 4;       // k-group of 8

  f32x4 acc[4];
#pragma unroll
  for (int mt = 0; mt < 4; ++mt) acc[mt] = (f32x4){0.f, 0.f, 0.f, 0.f};

#pragma unroll
  for (int kt = 0; kt < KPAD / 32; ++kt) {
    const int kbase = kt * 32 + kg * 8;
    bf16x8 bf = ldb8(W1f + ((size_t)(kbase >> 3) * N1 + n0 + lr) * 8);
#pragma unroll
    for (int mt = 0; mt < 4; ++mt) {
      bf16x8 af = ldb8(Hm + (size_t)(m0 + mt * 16 + lr) * KPAD + kbase);
      acc[mt] = __builtin_amdgcn_mfma_f32_16x16x32_bf16(af, bf, acc[mt], 0, 0, 0);
    }
  }

  const float bias = b1[n0 + lr];
  const int rb = kg * 4;
#pragma unroll
  for (int mt = 0; mt < 4; ++mt) {
#pragma unroll
    for (int r = 0; r < 4; ++r) {
      float v = acc[mt][r] + bias;
      v = v > 0.f ? v : 0.f;
      H2[(size_t)(m0 + mt * 16 + rb + r) * N1 + n0 + lr] = __float2bfloat16(v);
    }
  }
}

// ---------------------------------------------------------------------------
// Kernel 4: GEMM2 [B,128] = H2[B,256] x W2^T, +b2, ReLU, dot Wout, +fmlogit,
// sigmoid -> out. Block 256 thr = 4 waves; 64 rows; wave = 32 cols (2 ntiles).
// ---------------------------------------------------------------------------
__global__ __launch_bounds__(256) void gemm2out(
    const __hip_bfloat16* __restrict__ H2, const __hip_bfloat16* __restrict__ W2f,
    const float* __restrict__ b2, const float* __restrict__ Wout,
    const float* __restrict__ fmlogit, float* __restrict__ out) {
  const int wave = threadIdx.x >> 6;
  const int lane = threadIdx.x & 63;
  const int m0 = blockIdx.x * 64;
  const int n0 = wave * 32;
  const int lr = lane & 15;
  const int kg = lane >> 4;

  f32x4 acc[4][2];
#pragma unroll
  for (int mt = 0; mt < 4; ++mt) {
    acc[mt][0] = (f32x4){0.f, 0.f, 0.f, 0.f};
    acc[mt][1] = (f32x4){0.f, 0.f, 0.f, 0.f};
  }

#pragma unroll
  for (int kt = 0; kt < 256 / 32; ++kt) {
    const int kbase = kt * 32 + kg * 8;
    bf16x8 b0 = ldb8(W2f + ((size_t)(kbase >> 3) * N2 + n0 + lr) * 8);
    bf16x8 b1v = ldb8(W2f + ((size_t)(kbase >> 3) * N2 + n0 + 16 + lr) * 8);
#pragma unroll
    for (int mt = 0; mt < 4; ++mt) {
      bf16x8 af = ldb8(H2 + (size_t)(m0 + mt * 16 + lr) * N1 + kbase);
      acc[mt][0] = __builtin_amdgcn_mfma_f32_16x16x32_bf16(af, b0, acc[mt][0], 0, 0, 0);
      acc[mt][1] = __builtin_amdgcn_mfma_f32_16x16x32_bf16(af, b1v, acc[mt][1], 0, 0, 0);
    }
  }

  const float w0 = Wout[n0 + lr],      w1 = Wout[n0 + 16 + lr];
  const float bb0 = b2[n0 + lr],       bb1 = b2[n0 + 16 + lr];
  const int rb = kg * 4;

  __shared__ float red[64][4];
#pragma unroll
  for (int mt = 0; mt < 4; ++mt) {
#pragma unroll
    for (int r = 0; r < 4; ++r) {
      float v0 = acc[mt][0][r] + bb0; v0 = v0 > 0.f ? v0 : 0.f;
      float v1 = acc[mt][1][r] + bb1; v1 = v1 > 0.f ? v1 : 0.f;
      float v = v0 * w0 + v1 * w1;    // partial dnn_logit over this wave's 32 cols
#pragma unroll
      for (int off = 1; off < 16; off <<= 1)
        v += __shfl_xor(v, off, 16);
      if (lr == 0) red[mt * 16 + rb + r][wave] = v;
    }
  }
  __syncthreads();
  if (threadIdx.x < 64) {
    int row = threadIdx.x;
    float t = red[row][0] + red[row][1] + red[row][2] + red[row][3];
    float x = fmlogit[m0 + row] + t;
    out[m0 + row] = 1.f / (1.f + expf(-x));
  }
}

// ---------------------------------------------------------------------------
extern "C" void kernel_launch(void* const* d_in, const int* in_sizes, int n_in,
                              void* d_out, int out_size, void* d_ws, size_t ws_size,
                              hipStream_t stream) {
  const int*   Xs   = (const int*)d_in[0];
  const float* Xd   = (const float*)d_in[1];
  const float* linW = (const float*)d_in[2];
  const float* fmW  = (const float*)d_in[3];
  const float* dW   = (const float*)d_in[4];
  const float* dB   = (const float*)d_in[5];
  const float* W1   = (const float*)d_in[6];
  const float* b1   = (const float*)d_in[7];
  const float* W2   = (const float*)d_in[8];
  const float* b2   = (const float*)d_in[9];
  const float* Wout = (const float*)d_in[10];
  float* out = (float*)d_out;

  char* ws = (char*)d_ws;
  // workspace layout
  __hip_bfloat16* H   = (__hip_bfloat16*)(ws);                       // B*448*2 = 14,680,064
  __hip_bfloat16* H2  = (__hip_bfloat16*)(ws + 14680064);            // B*256*2 =  8,388,608
  float*          fml = (float*)(ws + 23068672);                     // B*4     =     65,536
  __hip_bfloat16* W1f = (__hip_bfloat16*)(ws + 23134208);            // 448*256*2 = 229,376
  __hip_bfloat16* W2f = (__hip_bfloat16*)(ws + 23363584);            // 256*128*2 =  65,536

  convert_weights<<<576, 256, 0, stream>>>(W1, W2, W1f, W2f);
  embed_fm<<<BTOT / 16, 256, 0, stream>>>(Xs, Xd, linW, fmW, dW, dB, H, fml);
  gemm1<<<dim3(BTOT / 64, 4), 256, 0, stream>>>(H, W1f, b1, H2);
  gemm2out<<<BTOT / 64, 256, 0, stream>>>(H2, W2f, b2, Wout, fml, out);
}

// Round 2
// 47.747 us; speedup vs baseline: 1.4130x; 1.4130x over previous
//
#include <hip/hip_runtime.h>
#include <hip/hip_bf16.h>
#include <math.h>

// Problem constants (DeepFM)
#define BTOT   16384
#define NF     26
#define VOCAB  100000
#define EDIM   16
#define DD     13
#define KPAD   448      // 429 padded to 14*32
#define KREAL  429
#define N1     256
#define N2     128
#define SPB    32       // samples per block
#define APAD   456      // A tile row stride (448+8): 912B = 228 dwords = 4 mod 32 banks
#define H2PAD  264      // H2 tile row stride (256+8): 528B = 132 dwords = 4 mod 32 banks

typedef __attribute__((ext_vector_type(8))) short bf16x8;
typedef __attribute__((ext_vector_type(4))) float f32x4;

static __device__ __forceinline__ bf16x8 ldb8(const __hip_bfloat16* p) {
  return *reinterpret_cast<const bf16x8*>(p);
}
static __device__ __forceinline__ bf16x8 ldsb8(const __hip_bfloat16* p) {
  return *reinterpret_cast<const bf16x8*>(p);
}

// ---------------------------------------------------------------------------
// Kernel 1: repack W1 [256][429] f32 -> W1f bf16 in B-fragment layout
//   element (k, n) stored at W1f[((k>>3)*N1 + n)*8 + (k&7)], zero pad k>=429.
// Same for W2 [128][256] -> W2f.
// ---------------------------------------------------------------------------
__global__ void convert_weights(const float* __restrict__ W1,
                                const float* __restrict__ W2,
                                __hip_bfloat16* __restrict__ W1f,
                                __hip_bfloat16* __restrict__ W2f) {
  int bid = blockIdx.x;
  int tid = threadIdx.x;
  if (bid < 448) {               // W1: k = bid (0..447), n = tid (0..255)
    int k = bid, n = tid;
    float v = (k < KREAL) ? W1[(size_t)n * KREAL + k] : 0.f;
    W1f[(((size_t)(k >> 3)) * N1 + n) * 8 + (k & 7)] = __float2bfloat16(v);
  } else {                       // W2: 256x128 elements, 128 blocks
    int g = (bid - 448) * 256 + tid;
    int k = g >> 7;              // 0..255
    int n = g & 127;             // 0..127
    float v = W2[(size_t)n * 256 + k];
    W2f[(((size_t)(k >> 3)) * N2 + n) * 8 + (k & 7)] = __float2bfloat16(v);
  }
}

// ---------------------------------------------------------------------------
// Fused kernel: per block of 32 samples:
//   phase 1: embedding gather -> LDS A tile (bf16), FM linear+cross -> fml
//   phase 2: GEMM1 (A[32,448] x W1f^T) +b1,ReLU -> LDS H2 tile (bf16)
//   phase 3: GEMM2 (H2[32,256] x W2f^T) +b2,ReLU, dot Wout
//   phase 4: + fml, sigmoid -> out
// 256 threads = 4 waves.
// ---------------------------------------------------------------------------
__global__ __launch_bounds__(256) void deepfm_fused(
    const int* __restrict__ Xs, const float* __restrict__ Xd,
    const float* __restrict__ linW, const float* __restrict__ fmW,
    const float* __restrict__ denseW, const float* __restrict__ denseB,
    const __hip_bfloat16* __restrict__ W1f, const float* __restrict__ b1,
    const __hip_bfloat16* __restrict__ W2f, const float* __restrict__ b2,
    const float* __restrict__ Wout, float* __restrict__ out) {

  __shared__ __hip_bfloat16 Ash[SPB][APAD];
  __shared__ __hip_bfloat16 H2sh[SPB][H2PAD];
  __shared__ float fmlsh[SPB];
  __shared__ float redsh[SPB][4];

  const int tid = threadIdx.x;
  const size_t blk0 = (size_t)blockIdx.x * SPB;

  // ---------------- phase 1: gather + FM ----------------
  {
    const int e  = tid & 15;        // embedding dim lane
    const int sq = tid >> 4;        // 0..15
#pragma unroll
    for (int half = 0; half < 2; ++half) {
      const int s = sq + half * 16;           // local sample 0..31
      const size_t b = blk0 + s;
      float sum = 0.f, sumsq = 0.f;
#pragma unroll
      for (int f = 0; f < NF; ++f) {
        int idx = Xs[b * NF + f];
        float v = fmW[((size_t)f * VOCAB + idx) * EDIM + e];
        sum += v;
        sumsq += v * v;
        Ash[s][f * EDIM + e] = __float2bfloat16(v);
      }
      float part = 0.5f * (sum * sum - sumsq);   // cross partial (per e)
      // linear part distributed over lanes: fields e and e+16
      {
        int idx = Xs[b * NF + e];
        if (e < NF) part += linW[(size_t)e * VOCAB + idx];   // e<16<26 always
        if (e + 16 < NF) {
          int idx2 = Xs[b * NF + e + 16];
          part += linW[(size_t)(e + 16) * VOCAB + idx2];
        }
      }
      // dense features: into A tile + linear dense dot
      float xd = (e < DD) ? Xd[b * DD + e] : 0.f;
      Ash[s][416 + e] = __float2bfloat16(xd);
      Ash[s][432 + e] = __float2bfloat16(0.f);
      if (e < DD) part += xd * denseW[e];
      // reduce over 16 lanes
#pragma unroll
      for (int off = 1; off < 16; off <<= 1)
        part += __shfl_xor(part, off);
      if (e == 0) fmlsh[s] = part + denseB[0];
    }
  }
  __syncthreads();

  // ---------------- phase 2: GEMM1 -> H2sh ----------------
  const int wave = tid >> 6;
  const int lane = tid & 63;
  const int lr = lane & 15;
  const int kg = lane >> 4;
  {
    const int n0 = wave * 64;
    f32x4 acc[2][4];
#pragma unroll
    for (int mt = 0; mt < 2; ++mt)
#pragma unroll
      for (int nt = 0; nt < 4; ++nt) acc[mt][nt] = (f32x4){0.f, 0.f, 0.f, 0.f};

#pragma unroll
    for (int kt = 0; kt < KPAD / 32; ++kt) {
      const int kbase = kt * 32 + kg * 8;
      bf16x8 af[2];
#pragma unroll
      for (int mt = 0; mt < 2; ++mt)
        af[mt] = ldsb8(&Ash[mt * 16 + lr][kbase]);
#pragma unroll
      for (int nt = 0; nt < 4; ++nt) {
        bf16x8 bf = ldb8(W1f + ((size_t)(kbase >> 3) * N1 + n0 + nt * 16 + lr) * 8);
        acc[0][nt] = __builtin_amdgcn_mfma_f32_16x16x32_bf16(af[0], bf, acc[0][nt], 0, 0, 0);
        acc[1][nt] = __builtin_amdgcn_mfma_f32_16x16x32_bf16(af[1], bf, acc[1][nt], 0, 0, 0);
      }
    }
    // epilogue: bias + relu -> H2sh
#pragma unroll
    for (int nt = 0; nt < 4; ++nt) {
      const int col = n0 + nt * 16 + lr;
      const float bias = b1[col];
#pragma unroll
      for (int mt = 0; mt < 2; ++mt) {
#pragma unroll
        for (int r = 0; r < 4; ++r) {
          float v = acc[mt][nt][r] + bias;
          v = v > 0.f ? v : 0.f;
          H2sh[mt * 16 + kg * 4 + r][col] = __float2bfloat16(v);
        }
      }
    }
  }
  __syncthreads();

  // ---------------- phase 3: GEMM2 + Wout dot ----------------
  {
    const int n0 = wave * 32;
    f32x4 acc[2][2];
#pragma unroll
    for (int mt = 0; mt < 2; ++mt)
#pragma unroll
      for (int nt = 0; nt < 2; ++nt) acc[mt][nt] = (f32x4){0.f, 0.f, 0.f, 0.f};

#pragma unroll
    for (int kt = 0; kt < N1 / 32; ++kt) {
      const int kbase = kt * 32 + kg * 8;
      bf16x8 af[2];
#pragma unroll
      for (int mt = 0; mt < 2; ++mt)
        af[mt] = ldsb8(&H2sh[mt * 16 + lr][kbase]);
#pragma unroll
      for (int nt = 0; nt < 2; ++nt) {
        bf16x8 bf = ldb8(W2f + ((size_t)(kbase >> 3) * N2 + n0 + nt * 16 + lr) * 8);
        acc[0][nt] = __builtin_amdgcn_mfma_f32_16x16x32_bf16(af[0], bf, acc[0][nt], 0, 0, 0);
        acc[1][nt] = __builtin_amdgcn_mfma_f32_16x16x32_bf16(af[1], bf, acc[1][nt], 0, 0, 0);
      }
    }
    // epilogue: bias + relu + Wout partial dot, reduce over 16 lanes
    float w0 = Wout[n0 + lr], w1 = Wout[n0 + 16 + lr];
    float bb0 = b2[n0 + lr], bb1 = b2[n0 + 16 + lr];
#pragma unroll
    for (int mt = 0; mt < 2; ++mt) {
#pragma unroll
      for (int r = 0; r < 4; ++r) {
        float v0 = acc[mt][0][r] + bb0; v0 = v0 > 0.f ? v0 : 0.f;
        float v1 = acc[mt][1][r] + bb1; v1 = v1 > 0.f ? v1 : 0.f;
        float v = v0 * w0 + v1 * w1;
#pragma unroll
        for (int off = 1; off < 16; off <<= 1)
          v += __shfl_xor(v, off);
        if (lr == 0) redsh[mt * 16 + kg * 4 + r][wave] = v;
      }
    }
  }
  __syncthreads();

  // ---------------- phase 4: combine + sigmoid ----------------
  if (tid < SPB) {
    const int row = tid;
    float t = redsh[row][0] + redsh[row][1] + redsh[row][2] + redsh[row][3];
    float x = fmlsh[row] + t;
    out[blk0 + row] = 1.f / (1.f + expf(-x));
  }
}

// ---------------------------------------------------------------------------
extern "C" void kernel_launch(void* const* d_in, const int* in_sizes, int n_in,
                              void* d_out, int out_size, void* d_ws, size_t ws_size,
                              hipStream_t stream) {
  const int*   Xs   = (const int*)d_in[0];
  const float* Xd   = (const float*)d_in[1];
  const float* linW = (const float*)d_in[2];
  const float* fmW  = (const float*)d_in[3];
  const float* dW   = (const float*)d_in[4];
  const float* dB   = (const float*)d_in[5];
  const float* W1   = (const float*)d_in[6];
  const float* b1   = (const float*)d_in[7];
  const float* W2   = (const float*)d_in[8];
  const float* b2   = (const float*)d_in[9];
  const float* Wout = (const float*)d_in[10];
  float* out = (float*)d_out;

  char* ws = (char*)d_ws;
  __hip_bfloat16* W1f = (__hip_bfloat16*)(ws);             // 448*256*2 = 229,376
  __hip_bfloat16* W2f = (__hip_bfloat16*)(ws + 229376);    // 256*128*2 =  65,536

  convert_weights<<<576, 256, 0, stream>>>(W1, W2, W1f, W2f);
  deepfm_fused<<<BTOT / SPB, 256, 0, stream>>>(
      Xs, Xd, linW, fmW, dW, dB, W1f, b1, W2f, b2, Wout, out);
}

// Round 3
// 32.378 us; speedup vs baseline: 2.0838x; 1.4747x over previous
//
#include <hip/hip_runtime.h>
#include <hip/hip_bf16.h>
#include <math.h>

// Problem constants (DeepFM)
#define BTOT   16384
#define NF     26
#define VOCAB  100000
#define EDIM   16
#define DD     13
#define KPAD   448      // 429 padded to 14*32
#define KREAL  429
#define N1     256
#define N2     128
#define SPB    32       // samples per block
#define APAD   456      // A tile row stride (448+8)
#define H2PAD  264      // H2 tile row stride (256+8)

typedef __attribute__((ext_vector_type(8))) short bf16x8;
typedef __attribute__((ext_vector_type(4))) short bf16x4;
typedef __attribute__((ext_vector_type(4))) float f32x4;

static __device__ __forceinline__ bf16x8 ldb8(const __hip_bfloat16* p) {
  return *reinterpret_cast<const bf16x8*>(p);
}
static __device__ __forceinline__ short f2bf(float f) {
  __hip_bfloat16 h = __float2bfloat16(f);
  return *reinterpret_cast<short*>(&h);
}

// ---------------------------------------------------------------------------
// Kernel 1: repack W1 [256][429] f32 -> W1f bf16 in B-fragment layout
//   element (k, n) stored at W1f[((k>>3)*N1 + n)*8 + (k&7)], zero pad k>=429.
// Same for W2 [128][256] -> W2f.
// ---------------------------------------------------------------------------
__global__ void convert_weights(const float* __restrict__ W1,
                                const float* __restrict__ W2,
                                __hip_bfloat16* __restrict__ W1f,
                                __hip_bfloat16* __restrict__ W2f) {
  int bid = blockIdx.x;
  int tid = threadIdx.x;
  if (bid < 448) {               // W1: k = bid, n = tid
    int k = bid, n = tid;
    float v = (k < KREAL) ? W1[(size_t)n * KREAL + k] : 0.f;
    W1f[(((size_t)(k >> 3)) * N1 + n) * 8 + (k & 7)] = __float2bfloat16(v);
  } else {                       // W2: 256x128 elements
    int g = (bid - 448) * 256 + tid;
    int k = g >> 7;
    int n = g & 127;
    float v = W2[(size_t)n * 256 + k];
    W2f[(((size_t)(k >> 3)) * N2 + n) * 8 + (k & 7)] = __float2bfloat16(v);
  }
}

// ---------------------------------------------------------------------------
// Fused kernel, 512 threads = 8 waves, 32 samples/block.
// Phase 1: float4 embedding gather -> LDS A tile (bf16), FM linear+cross.
//   thread t: sample s=t>>4; sub=t&15; q=sub&3 (e-quarter), g=sub>>2
//   (field-group): lane handles fields g,g+4,... quarter q (float4 each).
// Phase 2: GEMM1 (A[32,448] x W1f^T) +b1,ReLU -> LDS H2 tile.
// Phase 3: GEMM2 (H2[32,256] x W2f^T) +b2,ReLU, dot Wout.
// Phase 4: + fm logit, sigmoid -> out.
// ---------------------------------------------------------------------------
__global__ __launch_bounds__(512) void deepfm_fused(
    const int* __restrict__ Xs, const float* __restrict__ Xd,
    const float* __restrict__ linW, const float* __restrict__ fmW,
    const float* __restrict__ denseW, const float* __restrict__ denseB,
    const __hip_bfloat16* __restrict__ W1f, const float* __restrict__ b1,
    const __hip_bfloat16* __restrict__ W2f, const float* __restrict__ b2,
    const float* __restrict__ Wout, float* __restrict__ out) {

  __shared__ __hip_bfloat16 Ash[SPB][APAD];
  __shared__ __hip_bfloat16 H2sh[SPB][H2PAD];
  __shared__ float fmlsh[SPB];
  __shared__ float redsh[SPB][8];

  const int tid = threadIdx.x;
  const size_t blk0 = (size_t)blockIdx.x * SPB;

  // ---------------- phase 1: gather + FM ----------------
  {
    const int s   = tid >> 4;     // local sample 0..31
    const int sub = tid & 15;
    const int q   = sub & 3;      // e-quarter: dims q*4..q*4+3
    const int g   = sub >> 2;     // field group: fields g+4i
    const size_t b = blk0 + s;
    const int* xrow = Xs + b * NF;

    // prefetch indices (one dependent latency round)
    int idxs[7];
#pragma unroll
    for (int i = 0; i < 7; ++i) {
      int f = g + 4 * i;
      idxs[i] = (f < NF) ? xrow[f] : 0;
    }

    f32x4 sum = (f32x4){0.f, 0.f, 0.f, 0.f};
    f32x4 sumsq = (f32x4){0.f, 0.f, 0.f, 0.f};
    float part = 0.f;

#pragma unroll
    for (int i = 0; i < 7; ++i) {
      const int f = g + 4 * i;
      if (f < NF) {
        const float* row = fmW + ((size_t)f * VOCAB + idxs[i]) * EDIM;
        f32x4 v = *reinterpret_cast<const f32x4*>(row + q * 4);
        sum += v;
        sumsq += v * v;
        bf16x4 pk;
        pk[0] = f2bf(v[0]); pk[1] = f2bf(v[1]);
        pk[2] = f2bf(v[2]); pk[3] = f2bf(v[3]);
        *reinterpret_cast<bf16x4*>(&Ash[s][f * EDIM + q * 4]) = pk;
        if (q == (i & 3))
          part += linW[(size_t)f * VOCAB + idxs[i]];
      }
    }
    // reduce sum/sumsq over field-groups g (lanes xor 4, 8)
#pragma unroll
    for (int off = 4; off <= 8; off <<= 1) {
#pragma unroll
      for (int c = 0; c < 4; ++c) {
        sum[c] += __shfl_xor(sum[c], off);
        sumsq[c] += __shfl_xor(sumsq[c], off);
      }
    }
    if (g == 0) {                 // count each e-quarter's cross exactly once
      f32x4 c4 = sum * sum - sumsq;
      part += 0.5f * (c4[0] + c4[1] + c4[2] + c4[3]);
    }
    // dense features
    float xd = (sub < DD) ? Xd[b * DD + sub] : 0.f;
    Ash[s][416 + sub] = __float2bfloat16(xd);
    Ash[s][432 + sub] = __float2bfloat16(0.f);
    if (sub < DD) part += xd * denseW[sub];
    // reduce over the 16-lane group
#pragma unroll
    for (int off = 1; off < 16; off <<= 1)
      part += __shfl_xor(part, off);
    if (sub == 0) fmlsh[s] = part + denseB[0];
  }
  __syncthreads();

  // ---------------- phase 2: GEMM1 -> H2sh ----------------
  const int wave = tid >> 6;      // 0..7
  const int lane = tid & 63;
  const int lr = lane & 15;
  const int kg = lane >> 4;
  {
    const int n0 = wave * 32;
    f32x4 acc[2][2];
#pragma unroll
    for (int mt = 0; mt < 2; ++mt)
#pragma unroll
      for (int nt = 0; nt < 2; ++nt) acc[mt][nt] = (f32x4){0.f, 0.f, 0.f, 0.f};

#pragma unroll
    for (int kt = 0; kt < KPAD / 32; ++kt) {
      const int kbase = kt * 32 + kg * 8;
      bf16x8 af[2];
#pragma unroll
      for (int mt = 0; mt < 2; ++mt)
        af[mt] = *reinterpret_cast<const bf16x8*>(&Ash[mt * 16 + lr][kbase]);
#pragma unroll
      for (int nt = 0; nt < 2; ++nt) {
        bf16x8 bf = ldb8(W1f + ((size_t)(kbase >> 3) * N1 + n0 + nt * 16 + lr) * 8);
        acc[0][nt] = __builtin_amdgcn_mfma_f32_16x16x32_bf16(af[0], bf, acc[0][nt], 0, 0, 0);
        acc[1][nt] = __builtin_amdgcn_mfma_f32_16x16x32_bf16(af[1], bf, acc[1][nt], 0, 0, 0);
      }
    }
#pragma unroll
    for (int nt = 0; nt < 2; ++nt) {
      const int col = n0 + nt * 16 + lr;
      const float bias = b1[col];
#pragma unroll
      for (int mt = 0; mt < 2; ++mt) {
#pragma unroll
        for (int r = 0; r < 4; ++r) {
          float v = acc[mt][nt][r] + bias;
          v = v > 0.f ? v : 0.f;
          H2sh[mt * 16 + kg * 4 + r][col] = __float2bfloat16(v);
        }
      }
    }
  }
  __syncthreads();

  // ---------------- phase 3: GEMM2 + Wout dot ----------------
  {
    const int n0 = wave * 16;     // 8 waves x 16 = 128 cols
    f32x4 acc[2];
    acc[0] = (f32x4){0.f, 0.f, 0.f, 0.f};
    acc[1] = (f32x4){0.f, 0.f, 0.f, 0.f};

#pragma unroll
    for (int kt = 0; kt < N1 / 32; ++kt) {
      const int kbase = kt * 32 + kg * 8;
      bf16x8 bf = ldb8(W2f + ((size_t)(kbase >> 3) * N2 + n0 + lr) * 8);
#pragma unroll
      for (int mt = 0; mt < 2; ++mt) {
        bf16x8 af = *reinterpret_cast<const bf16x8*>(&H2sh[mt * 16 + lr][kbase]);
        acc[mt] = __builtin_amdgcn_mfma_f32_16x16x32_bf16(af, bf, acc[mt], 0, 0, 0);
      }
    }
    const float w0 = Wout[n0 + lr];
    const float bb0 = b2[n0 + lr];
#pragma unroll
    for (int mt = 0; mt < 2; ++mt) {
#pragma unroll
      for (int r = 0; r < 4; ++r) {
        float v = acc[mt][r] + bb0;
        v = v > 0.f ? v : 0.f;
        v *= w0;
#pragma unroll
        for (int off = 1; off < 16; off <<= 1)
          v += __shfl_xor(v, off);
        if (lr == 0) redsh[mt * 16 + kg * 4 + r][wave] = v;
      }
    }
  }
  __syncthreads();

  // ---------------- phase 4: combine + sigmoid ----------------
  if (tid < SPB) {
    const int row = tid;
    float t = 0.f;
#pragma unroll
    for (int w = 0; w < 8; ++w) t += redsh[row][w];
    float x = fmlsh[row] + t;
    out[blk0 + row] = 1.f / (1.f + expf(-x));
  }
}

// ---------------------------------------------------------------------------
extern "C" void kernel_launch(void* const* d_in, const int* in_sizes, int n_in,
                              void* d_out, int out_size, void* d_ws, size_t ws_size,
                              hipStream_t stream) {
  const int*   Xs   = (const int*)d_in[0];
  const float* Xd   = (const float*)d_in[1];
  const float* linW = (const float*)d_in[2];
  const float* fmW  = (const float*)d_in[3];
  const float* dW   = (const float*)d_in[4];
  const float* dB   = (const float*)d_in[5];
  const float* W1   = (const float*)d_in[6];
  const float* b1   = (const float*)d_in[7];
  const float* W2   = (const float*)d_in[8];
  const float* b2   = (const float*)d_in[9];
  const float* Wout = (const float*)d_in[10];
  float* out = (float*)d_out;

  char* ws = (char*)d_ws;
  __hip_bfloat16* W1f = (__hip_bfloat16*)(ws);             // 448*256*2 = 229,376
  __hip_bfloat16* W2f = (__hip_bfloat16*)(ws + 229376);    // 256*128*2 =  65,536

  convert_weights<<<576, 256, 0, stream>>>(W1, W2, W1f, W2f);
  deepfm_fused<<<BTOT / SPB, 512, 0, stream>>>(
      Xs, Xd, linW, fmW, dW, dB, W1f, b1, W2f, b2, Wout, out);
}

// Round 4
// 32.170 us; speedup vs baseline: 2.0972x; 1.0065x over previous
//
#include <hip/hip_runtime.h>
#include <hip/hip_bf16.h>
#include <math.h>

// Problem constants (DeepFM)
#define BTOT   16384
#define NF     26
#define VOCAB  100000
#define EDIM   16
#define DD     13
#define KPAD   448      // 429 padded to 14*32
#define KREAL  429
#define N1     256
#define N2     128
#define SPB    64       // samples per block
#define APAD   456      // A tile row stride (448+8)
#define H2PAD  264      // H2 tile row stride (256+8)

typedef __attribute__((ext_vector_type(8))) short bf16x8;
typedef __attribute__((ext_vector_type(4))) short bf16x4;
typedef __attribute__((ext_vector_type(4))) float f32x4;

static __device__ __forceinline__ bf16x8 ldb8(const __hip_bfloat16* p) {
  return *reinterpret_cast<const bf16x8*>(p);
}
static __device__ __forceinline__ short f2bf(float f) {
  __hip_bfloat16 h = __float2bfloat16(f);
  return *reinterpret_cast<short*>(&h);
}

// ---------------------------------------------------------------------------
// Kernel 1: repack weights -> bf16 B-fragment layout, coalesced reads.
//   W1  [256][429] f32 -> W1f[((k>>3)*256 + n)*8 + (k&7)]  (k padded to 448)
//   W2  [128][256] f32 -> W2f[((k>>3)*128 + n)*8 + (k&7)]
// blocks 0..255: W1 row n = bid, tid = k (0..511, active < 448)
// blocks 256..383: W2 row n = bid-256, tid = k (0..255)
// ---------------------------------------------------------------------------
__global__ __launch_bounds__(512) void convert_weights(
    const float* __restrict__ W1, const float* __restrict__ W2,
    __hip_bfloat16* __restrict__ W1f, __hip_bfloat16* __restrict__ W2f) {
  const int bid = blockIdx.x;
  const int k = threadIdx.x;
  if (bid < 256) {
    const int n = bid;
    if (k < 448) {
      float v = (k < KREAL) ? W1[(size_t)n * KREAL + k] : 0.f;
      W1f[(((size_t)(k >> 3)) * N1 + n) * 8 + (k & 7)] = __float2bfloat16(v);
    }
  } else {
    const int n = bid - 256;
    if (k < 256) {
      float v = W2[(size_t)n * 256 + k];
      W2f[(((size_t)(k >> 3)) * N2 + n) * 8 + (k & 7)] = __float2bfloat16(v);
    }
  }
}

// ---------------------------------------------------------------------------
// Fused kernel, 1024 threads = 16 waves, 64 samples/block, grid 256 (1/CU).
// Phase 1: float4 embedding gather -> LDS A tile (bf16), FM linear+cross.
//   thread t: sample s=t>>4; sub=t&15; q=sub&3 (e-quarter), g=sub>>2
//   (field-group): lane handles fields g+4i, quarter q (float4 each).
// Phase 2: GEMM1 (A[64,448] x W1f^T) +b1,ReLU -> LDS H2 tile.
//   wave w: cols n0=w*16, rows 0..63 (4 m-tiles).
// Phase 3: GEMM2 (H2[64,256] x W2f^T) +b2,ReLU, dot Wout.
//   wave w: col-slice c=w&7 (16 cols), m-half h=w>>3 (32 rows).
// Phase 4: + fm logit, sigmoid -> out.
// ---------------------------------------------------------------------------
__global__ __launch_bounds__(1024, 4) void deepfm_fused(
    const int* __restrict__ Xs, const float* __restrict__ Xd,
    const float* __restrict__ linW, const float* __restrict__ fmW,
    const float* __restrict__ denseW, const float* __restrict__ denseB,
    const __hip_bfloat16* __restrict__ W1f, const float* __restrict__ b1,
    const __hip_bfloat16* __restrict__ W2f, const float* __restrict__ b2,
    const float* __restrict__ Wout, float* __restrict__ out) {

  __shared__ __hip_bfloat16 Ash[SPB][APAD];
  __shared__ __hip_bfloat16 H2sh[SPB][H2PAD];
  __shared__ float fmlsh[SPB];
  __shared__ float redsh[SPB][8];

  const int tid = threadIdx.x;
  const size_t blk0 = (size_t)blockIdx.x * SPB;

  // ---------------- phase 1: gather + FM ----------------
  {
    const int s   = tid >> 4;     // local sample 0..63
    const int sub = tid & 15;
    const int q   = sub & 3;      // e-quarter: dims q*4..q*4+3
    const int g   = sub >> 2;     // field group: fields g+4i
    const size_t b = blk0 + s;
    const int* xrow = Xs + b * NF;

    // prefetch indices (one dependent latency round)
    int idxs[7];
#pragma unroll
    for (int i = 0; i < 7; ++i) {
      int f = g + 4 * i;
      idxs[i] = (f < NF) ? xrow[f] : 0;
    }

    f32x4 sum = (f32x4){0.f, 0.f, 0.f, 0.f};
    f32x4 sumsq = (f32x4){0.f, 0.f, 0.f, 0.f};
    float part = 0.f;

#pragma unroll
    for (int i = 0; i < 7; ++i) {
      const int f = g + 4 * i;
      if (f < NF) {
        const float* row = fmW + ((size_t)f * VOCAB + idxs[i]) * EDIM;
        f32x4 v = *reinterpret_cast<const f32x4*>(row + q * 4);
        sum += v;
        sumsq += v * v;
        bf16x4 pk;
        pk[0] = f2bf(v[0]); pk[1] = f2bf(v[1]);
        pk[2] = f2bf(v[2]); pk[3] = f2bf(v[3]);
        *reinterpret_cast<bf16x4*>(&Ash[s][f * EDIM + q * 4]) = pk;
        if (q == (i & 3))
          part += linW[(size_t)f * VOCAB + idxs[i]];
      }
    }
    // reduce sum/sumsq over field-groups g (lanes xor 4, 8)
#pragma unroll
    for (int off = 4; off <= 8; off <<= 1) {
#pragma unroll
      for (int c = 0; c < 4; ++c) {
        sum[c] += __shfl_xor(sum[c], off);
        sumsq[c] += __shfl_xor(sumsq[c], off);
      }
    }
    if (g == 0) {                 // count each e-quarter's cross exactly once
      f32x4 c4 = sum * sum - sumsq;
      part += 0.5f * (c4[0] + c4[1] + c4[2] + c4[3]);
    }
    // dense features
    float xd = (sub < DD) ? Xd[b * DD + sub] : 0.f;
    Ash[s][416 + sub] = __float2bfloat16(xd);
    Ash[s][432 + sub] = __float2bfloat16(0.f);
    if (sub < DD) part += xd * denseW[sub];
    // reduce over the 16-lane group
#pragma unroll
    for (int off = 1; off < 16; off <<= 1)
      part += __shfl_xor(part, off);
    if (sub == 0) fmlsh[s] = part + denseB[0];
  }
  __syncthreads();

  // ---------------- phase 2: GEMM1 -> H2sh ----------------
  const int wave = tid >> 6;      // 0..15
  const int lane = tid & 63;
  const int lr = lane & 15;
  const int kg = lane >> 4;
  {
    const int n0 = wave * 16;     // 16 waves x 16 cols = 256
    f32x4 acc[4];
#pragma unroll
    for (int mt = 0; mt < 4; ++mt) acc[mt] = (f32x4){0.f, 0.f, 0.f, 0.f};

#pragma unroll
    for (int kt = 0; kt < KPAD / 32; ++kt) {
      const int kbase = kt * 32 + kg * 8;
      bf16x8 bf = ldb8(W1f + ((size_t)(kbase >> 3) * N1 + n0 + lr) * 8);
#pragma unroll
      for (int mt = 0; mt < 4; ++mt) {
        bf16x8 af = *reinterpret_cast<const bf16x8*>(&Ash[mt * 16 + lr][kbase]);
        acc[mt] = __builtin_amdgcn_mfma_f32_16x16x32_bf16(af, bf, acc[mt], 0, 0, 0);
      }
    }
    const int col = n0 + lr;
    const float bias = b1[col];
#pragma unroll
    for (int mt = 0; mt < 4; ++mt) {
#pragma unroll
      for (int r = 0; r < 4; ++r) {
        float v = acc[mt][r] + bias;
        v = v > 0.f ? v : 0.f;
        H2sh[mt * 16 + kg * 4 + r][col] = __float2bfloat16(v);
      }
    }
  }
  __syncthreads();

  // ---------------- phase 3: GEMM2 + Wout dot ----------------
  {
    const int c  = wave & 7;      // col-slice (16 cols)
    const int h  = wave >> 3;     // m-half (32 rows)
    const int n0 = c * 16;
    f32x4 acc[2];
    acc[0] = (f32x4){0.f, 0.f, 0.f, 0.f};
    acc[1] = (f32x4){0.f, 0.f, 0.f, 0.f};

#pragma unroll
    for (int kt = 0; kt < N1 / 32; ++kt) {
      const int kbase = kt * 32 + kg * 8;
      bf16x8 bf = ldb8(W2f + ((size_t)(kbase >> 3) * N2 + n0 + lr) * 8);
#pragma unroll
      for (int mt = 0; mt < 2; ++mt) {
        bf16x8 af = *reinterpret_cast<const bf16x8*>(&H2sh[h * 32 + mt * 16 + lr][kbase]);
        acc[mt] = __builtin_amdgcn_mfma_f32_16x16x32_bf16(af, bf, acc[mt], 0, 0, 0);
      }
    }
    const float w0 = Wout[n0 + lr];
    const float bb0 = b2[n0 + lr];
#pragma unroll
    for (int mt = 0; mt < 2; ++mt) {
#pragma unroll
      for (int r = 0; r < 4; ++r) {
        float v = acc[mt][r] + bb0;
        v = v > 0.f ? v : 0.f;
        v *= w0;
#pragma unroll
        for (int off = 1; off < 16; off <<= 1)
          v += __shfl_xor(v, off);
        if (lr == 0) redsh[h * 32 + mt * 16 + kg * 4 + r][c] = v;
      }
    }
  }
  __syncthreads();

  // ---------------- phase 4: combine + sigmoid ----------------
  if (tid < SPB) {
    const int row = tid;
    float t = 0.f;
#pragma unroll
    for (int w = 0; w < 8; ++w) t += redsh[row][w];
    float x = fmlsh[row] + t;
    out[blk0 + row] = 1.f / (1.f + expf(-x));
  }
}

// ---------------------------------------------------------------------------
extern "C" void kernel_launch(void* const* d_in, const int* in_sizes, int n_in,
                              void* d_out, int out_size, void* d_ws, size_t ws_size,
                              hipStream_t stream) {
  const int*   Xs   = (const int*)d_in[0];
  const float* Xd   = (const float*)d_in[1];
  const float* linW = (const float*)d_in[2];
  const float* fmW  = (const float*)d_in[3];
  const float* dW   = (const float*)d_in[4];
  const float* dB   = (const float*)d_in[5];
  const float* W1   = (const float*)d_in[6];
  const float* b1   = (const float*)d_in[7];
  const float* W2   = (const float*)d_in[8];
  const float* b2   = (const float*)d_in[9];
  const float* Wout = (const float*)d_in[10];
  float* out = (float*)d_out;

  char* ws = (char*)d_ws;
  __hip_bfloat16* W1f = (__hip_bfloat16*)(ws);             // 448*256*2 = 229,376
  __hip_bfloat16* W2f = (__hip_bfloat16*)(ws + 229376);    // 256*128*2 =  65,536

  convert_weights<<<384, 512, 0, stream>>>(W1, W2, W1f, W2f);
  deepfm_fused<<<BTOT / SPB, 1024, 0, stream>>>(
      Xs, Xd, linW, fmW, dW, dB, W1f, b1, W2f, b2, Wout, out);
}